// Round 12
// baseline (101.056 us; speedup 1.0000x reference)
//
#include <hip/hip_runtime.h>
#include <cstdint>

// Bit-exact vs numpy reference: no FMA contraction anywhere in this TU.
#pragma clang fp contract(off)

#define NROWS 2000   // pred boxes per image
#define MCOLS 200    // gt boxes per image
#define BIMG  128    // images
#define NTHR  5      // thresholds 0.5..0.7 step 0.05
#define CAP   768    // per-image candidate entry capacity
#define NPMAX 1024   // next pow2 >= CAP (LDS sort buffer)
#define GB    8      // 8x8 grid of 128px cells (x1,y1 in [0,894])
#define NCELL (GB * GB)

// screening factor: inter >= t*uni  <=>  inter >= (t/(1+t))*(a1+a2).
// 0.4993/1.4993 = 0.333022 < 0.333200 = 0.4997/1.4997 -> every pair with
// exact IoU >= 0.4997 is flagged even with ~ulp predicate rounding.
#define CFAC 0.33302208f

typedef unsigned long long ull;

// --- Fused per-image kernel: gt-binning + screen + sort + greedy, all in
//     LDS. One block per image, 256 threads. Preds stay in registers
//     (8/thread, coalesced); only the 200 gt boxes are binned. Each pred
//     tests gt in its 3x3 cell neighborhood — a provable superset of all
//     inter>0 pairs (overlap needs |dx1|<120 ∧ |dy1|<120, both < 128).
//     Excluded pairs have inter==0 < ca1+ca2 so the hit SET equals the
//     all-pairs screen's; the bitonic sort erases append-order
//     nondeterminism ((row,col) unique -> keys unique -> total order). ---
__global__ void __launch_bounds__(256) fused_kernel(
        const float4* __restrict__ pred, const float4* __restrict__ gt,
        float* __restrict__ perimg) {
    __shared__ float4 gco[MCOLS];          // binned gt boxes
    __shared__ int    gid[MCOLS];          // original gt ids
    __shared__ int    goff_l[NCELL + 1];   // exclusive cell offsets
    __shared__ int    gcur[NCELL];         // counts -> scatter cursors
    __shared__ ull    keys[NPMAX];         // candidate keys (sorted in place)
    __shared__ int    nsh;                 // candidate count
    __shared__ float  precs[NTHR];

    const int b = blockIdx.x, tid = threadIdx.x;

    if (tid < NCELL) gcur[tid] = 0;
    if (tid == 0) nsh = 0;
    __syncthreads();

    // 1) load gt, count cells
    float4 gr = make_float4(0.f, 0.f, 0.f, 0.f);
    int gbn = -1;
    if (tid < MCOLS) {
        gr = gt[(size_t)b * MCOLS + tid];
        int cx = (int)gr.x >> 7, cy = (int)gr.y >> 7;
        cx = cx < 0 ? 0 : (cx > GB - 1 ? GB - 1 : cx);
        cy = cy < 0 ? 0 : (cy > GB - 1 ? GB - 1 : cy);
        gbn = cy * GB + cx;
        atomicAdd(&gcur[gbn], 1);
    }
    __syncthreads();

    // 2) exclusive scan over 64 cells in wave 0 (lane == cell)
    if (tid < 64) {
        const int v = gcur[tid];
        int inc = v;
#pragma unroll
        for (int off = 1; off < 64; off <<= 1) {
            const int u = __shfl_up(inc, off);
            if (tid >= off) inc += u;
        }
        goff_l[tid + 1] = inc;
        if (tid == 0) goff_l[0] = 0;
        gcur[tid] = inc - v;               // exclusive offset -> cursor
    }
    __syncthreads();

    // 3) scatter gt into binned order
    if (gbn >= 0) {
        const int idx = atomicAdd(&gcur[gbn], 1);
        gco[idx] = gr;
        gid[idx] = tid;
    }
    __syncthreads();

    // 4) screen: 8 register-resident preds per thread vs 3x3 neighborhood
#pragma unroll
    for (int k = 0; k < 8; ++k) {
        const int r = tid + k * 256;
        if (r < NROWS) {
            const float4 p = pred[(size_t)b * NROWS + r];   // coalesced
            const float a1 = (p.z - p.x) * (p.w - p.y);
            const float ca1 = CFAC * a1;
            int cx = (int)p.x >> 7, cy = (int)p.y >> 7;
            cx = cx < 0 ? 0 : (cx > GB - 1 ? GB - 1 : cx);
            cy = cy < 0 ? 0 : (cy > GB - 1 ? GB - 1 : cy);
            const int xlo = cx > 0 ? cx - 1 : 0;
            const int xhi = cx < GB - 1 ? cx + 1 : GB - 1;
            const int ylo = cy > 0 ? cy - 1 : 0;
            const int yhi = cy < GB - 1 ? cy + 1 : GB - 1;
            for (int gy = ylo; gy <= yhi; ++gy) {
                const int lo = goff_l[gy * GB + xlo];
                const int hi = goff_l[gy * GB + xhi + 1];
                for (int j = lo; j < hi; ++j) {
                    const float4 gb = gco[j];
                    const float a2 = (gb.z - gb.x) * (gb.w - gb.y);  // exact ref product
                    const float ltx = fmaxf(p.x, gb.x), lty = fmaxf(p.y, gb.y);
                    const float rbx = fminf(p.z, gb.z), rby = fminf(p.w, gb.w);
                    const float wx = fmaxf(rbx - ltx, 0.0f), wy = fmaxf(rby - lty, 0.0f);
                    const float inter = wx * wy;
                    if (inter >= ca1 + CFAC * a2) {                  // rare
                        const float uni = (a1 + a2) - inter;         // reference order
                        const float iou = inter / uni;               // exact IEEE
                        const int idx = atomicAdd(&nsh, 1);
                        if (idx < CAP)
                            keys[idx] = ((ull)r << 40)
                                | ((ull)(__float_as_uint(iou) ^ 0xFFFFFFFFu) << 8)
                                | (ull)gid[j];
                    }
                }
            }
        }
    }
    __syncthreads();

    // 5) bitonic sort keys in place (deterministic total order)
    const int n = min(nsh, CAP);
    int np = 128;
    while (np < n) np <<= 1;               // n<=768 -> np<=1024
    for (int i = tid; i < np; i += 256)
        if (i >= n) keys[i] = ~0ull;       // sentinels sort last
    __syncthreads();
    for (int k = 2; k <= np; k <<= 1) {
        for (int j = k >> 1; j > 0; j >>= 1) {
            for (int i = tid; i < np; i += 256) {
                const int ixj = i ^ j;
                if (ixj > i) {
                    const ull a = keys[i], c = keys[ixj];
                    if ((a > c) == ((i & k) == 0)) { keys[i] = c; keys[ixj] = a; }
                }
            }
            __syncthreads();
        }
    }

    // 6) 5 lanes replay exact greedy branchlessly (200-bit mask in 4 ulls)
    if (tid < NTHR) {
        // match np.arange(0.5, 0.75, 0.05): start + i*step in double, cast f32
        const float thr = (float)(0.5 + 0.05 * (double)tid);
        const uint thr_inv = __float_as_uint(thr) ^ 0xFFFFFFFFu;
        ull m0 = 0, m1 = 0, m2 = 0, m3 = 0;
        int tp = 0, cur = -1;
        bool done = false;
#pragma unroll 4
        for (int e = 0; e < n; ++e) {
            const ull key = keys[e];              // induction addr -> prefetchable
            const int row = (int)(key >> 40);
            const int col = (int)(key & 0xFFull);
            const uint ib  = (uint)(key >> 8);    // inverted iou bits (low = high iou)
            const bool newrow = (row != cur);
            cur = row;
            const bool undecided = newrow || !done;
            const int w = col >> 6;
            const ull bit = 1ull << (col & 63);
            const ull mm = (w == 0) ? m0 : (w == 1) ? m1 : (w == 2) ? m2 : m3;
            const bool decide = undecided && ((mm & bit) == 0);  // best unmatched col
            const bool hit = decide && (ib <= thr_inv);          // iou >= thr
            tp += hit ? 1 : 0;
            const ull sb = hit ? bit : 0ull;
            m0 |= (w == 0) ? sb : 0ull;
            m1 |= (w == 1) ? sb : 0ull;
            m2 |= (w == 2) ? sb : 0ull;
            m3 |= (w == 3) ? sb : 0ull;
            done = decide || (done && !newrow);
        }
        // fp = NROWS - tp, fn = MCOLS - tp  =>  prec = tp / (N + M - tp)
        precs[tid] = (float)tp / (float)(NROWS + MCOLS - tp);
    }
    __syncthreads();
    if (tid == 0) {
        float s = 0.0f;
#pragma unroll
        for (int t = 0; t < NTHR; ++t) s += precs[t];
        perimg[b] = s / (float)NTHR;
    }
}

// --- finalize: mean over images ---
__global__ void __launch_bounds__(64) finalize_kernel(
        const float* __restrict__ perimg, float* __restrict__ out) {
    const int lane = threadIdx.x;
    float s = perimg[lane] + perimg[lane + 64];
#pragma unroll
    for (int off = 32; off; off >>= 1) s += __shfl_xor(s, off);
    if (lane == 0) out[0] = s / (float)BIMG;
}

extern "C" void kernel_launch(void* const* d_in, const int* in_sizes, int n_in,
                              void* d_out, int out_size, void* d_ws, size_t ws_size,
                              hipStream_t stream) {
    const float4* pred = (const float4*)d_in[0];
    const float4* gt   = (const float4*)d_in[1];
    float* out = (float*)d_out;
    float* perimg = (float*)d_ws;          // BIMG floats

    fused_kernel<<<dim3(BIMG), dim3(256), 0, stream>>>(pred, gt, perimg);
    finalize_kernel<<<dim3(1), dim3(64), 0, stream>>>(perimg, out);
}

// Round 13
// 77.367 us; speedup vs baseline: 1.3062x; 1.3062x over previous
//
#include <hip/hip_runtime.h>
#include <cstdint>

// Bit-exact vs numpy reference: no FMA contraction anywhere in this TU.
#pragma clang fp contract(off)

#define NROWS 2000   // pred boxes per image
#define MCOLS 200    // gt boxes per image
#define BIMG  128    // images
#define NTHR  5      // thresholds 0.5..0.7 step 0.05
#define CAP   768    // per-image candidate entry capacity (expected ~76)
#define NPMAX 1024   // next pow2 >= CAP (LDS sort buffer)
#define GB    8      // 8x8 grid of 128px cells
#define NCELL (GB * GB)
#define PCHUNK 250   // preds per screen block (8 chunks x 250 = 2000)

// screening factor: inter >= t*uni  <=>  inter >= (t/(1+t))*(a1+a2).
// 0.4993/1.4993 = 0.333022 < 0.333200 = 0.4997/1.4997 -> every pair with
// exact IoU >= 0.4997 is flagged even with ~ulp predicate rounding.
#define CFAC 0.33302208f

typedef unsigned long long ull;

// --- Phase 1: self-sufficient screen. Block = (pred-chunk, image), 256 thr.
//     Each block re-bins the 200 gt boxes into LDS (SoA: divergent 4B reads
//     are ~2-way bank-aliased = free), then each thread screens ONE pred
//     (coalesced global read) against its 3x3 cell neighborhood — a provable
//     superset of all inter>0 pairs (overlap needs |dx1|<120 ∧ |dy1|<120,
//     both < 128; excluded pairs have inter==0 < ca1+ca2 > 0). Hit SET is
//     identical to the all-pairs screen; the sort in match erases
//     append-order nondeterminism. ---
__global__ void __launch_bounds__(256) screen_kernel(
        const float4* __restrict__ pred, const float4* __restrict__ gt,
        int* __restrict__ counters, ull* __restrict__ entries) {
    __shared__ float gx[MCOLS], gy[MCOLS], gz[MCOLS], gw[MCOLS], ga2[MCOLS];
    __shared__ int   gid_l[MCOLS];
    __shared__ int   goff_l[NCELL + 1];
    __shared__ int   gcur[NCELL];
    const int b = blockIdx.y, tid = threadIdx.x;

    if (tid < NCELL) gcur[tid] = 0;
    __syncthreads();

    // 1) load gt, count cells
    float4 gr = make_float4(0.f, 0.f, 0.f, 0.f);
    int gbn = -1;
    if (tid < MCOLS) {
        gr = gt[(size_t)b * MCOLS + tid];
        int cx = (int)gr.x >> 7, cy = (int)gr.y >> 7;
        cx = cx < 0 ? 0 : (cx > GB - 1 ? GB - 1 : cx);
        cy = cy < 0 ? 0 : (cy > GB - 1 ? GB - 1 : cy);
        gbn = cy * GB + cx;
        atomicAdd(&gcur[gbn], 1);
    }
    __syncthreads();

    // 2) exclusive scan over 64 cells in wave 0 (lane == cell)
    if (tid < 64) {
        const int v = gcur[tid];
        int inc = v;
#pragma unroll
        for (int off = 1; off < 64; off <<= 1) {
            const int u = __shfl_up(inc, off);
            if (tid >= off) inc += u;
        }
        goff_l[tid + 1] = inc;
        if (tid == 0) goff_l[0] = 0;
        gcur[tid] = inc - v;               // exclusive offset -> scatter cursor
    }
    __syncthreads();

    // 3) scatter gt into binned SoA order
    if (gbn >= 0) {
        const int idx = atomicAdd(&gcur[gbn], 1);
        gx[idx] = gr.x; gy[idx] = gr.y; gz[idx] = gr.z; gw[idx] = gr.w;
        ga2[idx] = (gr.z - gr.x) * (gr.w - gr.y);   // exact reference product
        gid_l[idx] = tid;
    }
    __syncthreads();

    // 4) one pred per thread vs 3x3 neighborhood
    if (tid < PCHUNK) {
        const int r = blockIdx.x * PCHUNK + tid;
        const float4 p = pred[(size_t)b * NROWS + r];   // coalesced
        const float a1 = (p.z - p.x) * (p.w - p.y);
        const float ca1 = CFAC * a1;
        int cx = (int)p.x >> 7, cy = (int)p.y >> 7;
        cx = cx < 0 ? 0 : (cx > GB - 1 ? GB - 1 : cx);
        cy = cy < 0 ? 0 : (cy > GB - 1 ? GB - 1 : cy);
        const int xlo = cx > 0 ? cx - 1 : 0;
        const int xhi = cx < GB - 1 ? cx + 1 : GB - 1;
        const int ylo = cy > 0 ? cy - 1 : 0;
        const int yhi = cy < GB - 1 ? cy + 1 : GB - 1;
        for (int gyy = ylo; gyy <= yhi; ++gyy) {
            const int lo = goff_l[gyy * GB + xlo];
            const int hi = goff_l[gyy * GB + xhi + 1];
            for (int j = lo; j < hi; ++j) {
                const float a2 = ga2[j];
                const float ltx = fmaxf(p.x, gx[j]), lty = fmaxf(p.y, gy[j]);
                const float rbx = fminf(p.z, gz[j]), rby = fminf(p.w, gw[j]);
                const float wx = fmaxf(rbx - ltx, 0.0f), wy = fmaxf(rby - lty, 0.0f);
                const float inter = wx * wy;
                if (inter >= ca1 + CFAC * a2) {             // rare
                    const float uni = (a1 + a2) - inter;    // reference order
                    const float iou = inter / uni;          // exact IEEE
                    const int idx = atomicAdd(&counters[b], 1);
                    if (idx < CAP)
                        entries[(size_t)b * CAP + idx] = ((ull)r << 40)
                            | ((ull)(__float_as_uint(iou) ^ 0xFFFFFFFFu) << 8)
                            | (ull)gid_l[j];
                }
            }
        }
    }
}

// --- Phase 2: per image: bitonic-sort candidate keys (deterministic total
//     order erases atomic append order), then 5 lanes replay exact greedy
//     branchlessly in registers (200-bit matched mask in 4 ulls). ---
__global__ void __launch_bounds__(256) match_kernel(
        const int* __restrict__ counters, const ull* __restrict__ entries,
        float* __restrict__ perimg) {
    __shared__ ull   keys[NPMAX];
    __shared__ float precs[NTHR];
    const int b = blockIdx.x;
    const int tid = threadIdx.x;
    const int n = min(counters[b], CAP);

    int np = 256;
    while (np < n) np <<= 1;                 // n<=768 -> np<=1024
    for (int i = tid; i < np; i += 256)
        keys[i] = (i < n) ? entries[(size_t)b * CAP + i] : ~0ull;  // sentinels last
    __syncthreads();

    for (int k = 2; k <= np; k <<= 1) {
        for (int j = k >> 1; j > 0; j >>= 1) {
            for (int i = tid; i < np; i += 256) {
                const int ixj = i ^ j;
                if (ixj > i) {
                    const ull a = keys[i], c = keys[ixj];
                    if ((a > c) == ((i & k) == 0)) { keys[i] = c; keys[ixj] = a; }
                }
            }
            __syncthreads();
        }
    }

    if (tid < NTHR) {
        // match np.arange(0.5, 0.75, 0.05): start + i*step in double, cast f32
        const float thr = (float)(0.5 + 0.05 * (double)tid);
        const uint thr_inv = __float_as_uint(thr) ^ 0xFFFFFFFFu;
        ull m0 = 0, m1 = 0, m2 = 0, m3 = 0;
        int tp = 0, cur = -1;
        bool done = false;
#pragma unroll 4
        for (int e = 0; e < n; ++e) {
            const ull key = keys[e];              // induction addr -> prefetchable
            const int row = (int)(key >> 40);
            const int col = (int)(key & 0xFFull);
            const uint ib  = (uint)(key >> 8);    // inverted iou bits (low = high iou)
            const bool newrow = (row != cur);
            cur = row;
            const bool undecided = newrow || !done;
            const int w = col >> 6;
            const ull bit = 1ull << (col & 63);
            const ull mm = (w == 0) ? m0 : (w == 1) ? m1 : (w == 2) ? m2 : m3;
            const bool decide = undecided && ((mm & bit) == 0);  // best unmatched col
            const bool hit = decide && (ib <= thr_inv);          // iou >= thr
            tp += hit ? 1 : 0;
            const ull sb = hit ? bit : 0ull;
            m0 |= (w == 0) ? sb : 0ull;
            m1 |= (w == 1) ? sb : 0ull;
            m2 |= (w == 2) ? sb : 0ull;
            m3 |= (w == 3) ? sb : 0ull;
            done = decide || (done && !newrow);
        }
        // fp = NROWS - tp, fn = MCOLS - tp  =>  prec = tp / (N + M - tp)
        precs[tid] = (float)tp / (float)(NROWS + MCOLS - tp);
    }
    __syncthreads();
    if (tid == 0) {
        float s = 0.0f;
#pragma unroll
        for (int t = 0; t < NTHR; ++t) s += precs[t];
        perimg[b] = s / (float)NTHR;
    }
}

// --- Phase 3: mean over images ---
__global__ void __launch_bounds__(64) finalize_kernel(
        const float* __restrict__ perimg, float* __restrict__ out) {
    const int lane = threadIdx.x;
    float s = perimg[lane] + perimg[lane + 64];
#pragma unroll
    for (int off = 32; off; off >>= 1) s += __shfl_xor(s, off);
    if (lane == 0) out[0] = s / (float)BIMG;
}

extern "C" void kernel_launch(void* const* d_in, const int* in_sizes, int n_in,
                              void* d_out, int out_size, void* d_ws, size_t ws_size,
                              hipStream_t stream) {
    const float4* pred = (const float4*)d_in[0];
    const float4* gt   = (const float4*)d_in[1];
    float* out = (float*)d_out;

    int*   cnt     = (int*)d_ws;                                   // 128 ints
    ull*   entries = (ull*)((char*)d_ws + 512);                    // 128*CAP u64
    float* perimg  = (float*)((char*)d_ws + 512 + (size_t)BIMG * CAP * 8);

    (void)hipMemsetAsync(cnt, 0, BIMG * sizeof(int), stream);      // capturable

    screen_kernel<<<dim3(NROWS / PCHUNK, BIMG), dim3(256), 0, stream>>>(
        pred, gt, cnt, entries);

    match_kernel<<<dim3(BIMG), dim3(256), 0, stream>>>(cnt, entries, perimg);

    finalize_kernel<<<dim3(1), dim3(64), 0, stream>>>(perimg, out);
}